// Round 10
// baseline (60.383 us; speedup 1.0000x reference)
//
#include <hip/hip_runtime.h>
#include <math.h>

// ArcFace fused loss, B=512, C=100000, float32.
// loss_b = logsumexp_c(64*arcrow) - 64*theta_valid ; out = mean_b loss_b
// Single kernel. Combined loop: per iter {poll LDS flag -> NT-load y -> load x
// -> exp-sum x -> check y}; on flag, break to a pure-x tail loop (i preserved,
// so every x element is processed exactly once). y (HBM, nontemporal -- stays
// out of L3 so x's 200 MB < 256 MB L3 stays resident) streams CONCURRENTLY
// with x (L3) instead of serially before it. Expected y traffic ~52%.
// The finder lane captures the label logit from its already-loaded x vector
// (no separate global load). Mean via one device-scope atomicAdd per block;
// d_out zeroed by a captured hipMemsetAsync node (no cross-replay carry).

#define BB 512
#define CC 100000
#define C4 (CC / 4)           // 25000 float4 per row
#define BLK 1024

// 64 * log2(e), for exp(64x-64) = exp2(K*x - K)
#define K64 92.33248261689366f

typedef unsigned int u32x4 __attribute__((ext_vector_type(4)));
typedef float f32x4 __attribute__((ext_vector_type(4)));

__device__ __forceinline__ float wave_reduce_add(float v) {
    #pragma unroll
    for (int off = 32; off > 0; off >>= 1)
        v += __shfl_down(v, off, 64);
    return v;
}

__device__ __forceinline__ float e64(float x) {
    return __builtin_amdgcn_exp2f(fmaf(K64, x, -K64));   // v_exp_f32
}

__global__ __launch_bounds__(BLK) void arcface_rows(const float* __restrict__ y_true,
                                                    const float* __restrict__ logits,
                                                    float* __restrict__ out) {
    const int row = blockIdx.x;
    const int tid = threadIdx.x;
    const u32x4* __restrict__ y4 = (const u32x4*)(y_true + (size_t)row * CC);
    const f32x4* __restrict__ x4 = (const f32x4*)(logits + (size_t)row * CC);

    __shared__ int s_found;
    __shared__ float s_val;
    __shared__ float s_sum[BLK / 64];

    if (tid == 0) s_found = 0;
    __syncthreads();
    volatile int* vfound = &s_found;

    float s0 = 0.0f, s1 = 0.0f;
    int i = tid;

    // ---- combined loop: y-scan (HBM/NT) + x exp-sum (L3), concurrent streams ----
    #pragma unroll 1
    for (; i < C4; i += BLK) {
        if (*vfound) break;                 // poll; exit lag <= 1 iteration
        const u32x4 u = __builtin_nontemporal_load(&y4[i]);
        const f32x4 x = x4[i];
        s0 += e64(x.x); s1 += e64(x.y); s0 += e64(x.z); s1 += e64(x.w);
        if (u.x | u.y | u.z | u.w) {        // exactly one finder lane per row
            s_val = u.x ? x.x : (u.y ? x.y : (u.z ? x.z : x.w));
            *vfound = 1;
        }
    }
    // ---- tail: pure x exp-sum from wherever we stopped ----
    #pragma unroll 1
    for (; i < C4; i += BLK) {
        const f32x4 x = x4[i];
        s0 += e64(x.x); s1 += e64(x.y); s0 += e64(x.z); s1 += e64(x.w);
    }

    float s = wave_reduce_add(s0 + s1);
    if ((tid & 63) == 0) s_sum[tid >> 6] = s;
    __syncthreads();   // also publishes s_val (finder wrote before its barrier)

    if (tid == 0) {
        float total = 0.0f;
        #pragma unroll
        for (int w = 0; w < BLK / 64; ++w) total += s_sum[w];

        const float val = s_val;
        // margin1=1, margin2=0.5, margin3=0
        const float THRESH = -0.8775825618903728f;  // cos(pi - 0.5)
        const float theta = cosf(acosf(val) + 0.5f);
        const float tv = (val > THRESH) ? theta : (-2.0f - theta);

        // swap label term: remove exp(64v-64), add exp(64*tv-64)
        total += e64(tv) - e64(val);

        // loss_b = (64 + log(total)) - 64*tv ; contribute loss_b/B to the mean
        const float loss = 64.0f + logf(total) - 64.0f * tv;
        atomicAdd(out, loss * (1.0f / (float)BB));   // device-scope by default
    }
}

extern "C" void kernel_launch(void* const* d_in, const int* in_sizes, int n_in,
                              void* d_out, int out_size, void* d_ws, size_t ws_size,
                              hipStream_t stream) {
    const float* y_true = (const float*)d_in[0];
    const float* logits = (const float*)d_in[1];
    float* out = (float*)d_out;

    hipMemsetAsync(out, 0, sizeof(float), stream);   // graph memset node
    arcface_rows<<<BB, BLK, 0, stream>>>(y_true, logits, out);
}